// Round 11
// baseline (218.193 us; speedup 1.0000x reference)
//
#include <hip/hip_runtime.h>
#include <hip/hip_bf16.h>
#include <stdint.h>

// MHA: B=2, S=2048, DIM=1024, H=16, HD=64, causal. fp32 I/O, bf16 MFMA internal.
// Flash rebuilt as KEY-SPLIT: wave w owns keys [w*16,w*16+16) of each tile and
// accumulates partial O/l for all 64 q; cross-wave reduce once at the end.
// Rationale (r10): LDS pipe ~70% busy was the wall — all 4 waves duplicated
// kf/vf reads (4x) and P did a full LDS roundtrip. Key-split cuts LDS/iter
// ~3x and eliminates P roundtrip entirely: with K-dim=16, S^T's C-layout
// (row=key=g*4+reg) IS the PV B-operand layout (k=quad*4+j) — in-register
// fp32->bf16 convert, zero-padded into the 16x16x32 MFMA shape.

typedef short s16x8 __attribute__((ext_vector_type(8)));
typedef float f32x4 __attribute__((ext_vector_type(4)));

#define MFMA_BF16 __builtin_amdgcn_mfma_f32_16x16x32_bf16

static __device__ __forceinline__ unsigned short f2bf(float f) {
    union { float f; unsigned u; } x{f};
    unsigned r = x.u + 0x7fff + ((x.u >> 16) & 1);   // RNE
    return (unsigned short)(r >> 16);
}
static __device__ __forceinline__ unsigned pk2h(float a, float b) {
    __hip_bfloat162 h = __float22bfloat162_rn(float2{a, b});   // v_cvt_pk_bf16_f32
    return *(unsigned*)&h;
}
static __device__ __forceinline__ void ald16(unsigned short* lds, const unsigned short* g) {
    __builtin_amdgcn_global_load_lds(
        (const __attribute__((address_space(1))) unsigned int*)g,
        (__attribute__((address_space(3))) unsigned int*)lds, 16, 0, 0);
}

#define QSCL 0.18033688f   // 0.125 * log2(e): folded into Q at proj epilogue

// ---------------------------------------------------------------------------
// convert_all: q,k,v (4M elems each) + wq,wk,wv,wo (1M each) fp32 -> bf16,
// contiguous at ws base: [Qb|Kb|Vb|Wq|Wk|Wv|Wo]. grid 8192x256.
// ---------------------------------------------------------------------------
__global__ __launch_bounds__(256) void convert_all_kernel(
        const float* __restrict__ q, const float* __restrict__ k,
        const float* __restrict__ v,
        const float* __restrict__ wq, const float* __restrict__ wk,
        const float* __restrict__ wv, const float* __restrict__ wo,
        unsigned short* __restrict__ dst) {
    const size_t idx = ((size_t)blockIdx.x * 256 + threadIdx.x) * 8;
    const int region = (int)(idx >> 22);
    const float* src;
    size_t off;
    if (region == 0)      { src = q; off = idx; }
    else if (region == 1) { src = k; off = idx & 4194303; }
    else if (region == 2) { src = v; off = idx & 4194303; }
    else {
        const int wsel = (int)((idx >> 20) & 3);
        src = wsel == 0 ? wq : wsel == 1 ? wk : wsel == 2 ? wv : wo;
        off = idx & 1048575;
    }
    const float4* p = (const float4*)(src + off);
    float4 a = p[0], b = p[1];
    uint4 u;
    u.x = pk2h(a.x, a.y); u.y = pk2h(a.z, a.w);
    u.z = pk2h(b.x, b.y); u.w = pk2h(b.z, b.w);
    *(uint4*)(dst + idx) = u;
}

// ---------------------------------------------------------------------------
// proj3b: C[4096x1024] = A_bf16 @ W_bf16^T. 128x128 tile, BK=32, full ald16
// staging. grid (32,8,3): x->m (XCD-local A), y->n.
// z==0 scaled by QSCL. z==2: transpose epilogue -> Xvt[dim][token].
// ---------------------------------------------------------------------------
__global__ __launch_bounds__(256) void proj3b_kernel(
        const unsigned short* __restrict__ Qb, const unsigned short* __restrict__ Kb,
        const unsigned short* __restrict__ Vb, const unsigned short* __restrict__ Wb,
        unsigned short* __restrict__ Xq, unsigned short* __restrict__ Xk,
        unsigned short* __restrict__ Xvt) {
    constexpr int Kd = 1024;
    __shared__ union {
        struct { unsigned short A[128 * 32]; unsigned short B[128 * 32]; } s;
        unsigned short T[4 * 64 * 68];          // per-wave transpose tile (z==2)
    } sm;

    const int z = blockIdx.z;
    const unsigned short* A  = z == 0 ? Qb : z == 1 ? Kb : Vb;
    const unsigned short* Bw = Wb + (size_t)z * 1048576;

    const int t = threadIdx.x;
    const int m0 = blockIdx.x * 128, n0 = blockIdx.y * 128;
    const int w = t >> 6, lane = t & 63, fr = lane & 15, g = lane >> 4;
    const int wm = (w >> 1) * 64, wn = (w & 1) * 64;
    const int brow = t >> 2;
    const int cB = (t & 3) ^ ((t >> 3) & 3);             // permuted source chunk
    const int sB = g ^ ((fr >> 1) & 3);                  // frag-read slot

    f32x4 acc[4][4] = {};

    for (int k0 = 0; k0 < Kd; k0 += 32) {
        ald16(sm.s.A + (size_t)w * 512,        A  + (size_t)(m0 + brow) * Kd + k0 + cB * 8);
        ald16(sm.s.A + 2048 + (size_t)w * 512, A  + (size_t)(m0 + 64 + brow) * Kd + k0 + cB * 8);
        ald16(sm.s.B + (size_t)w * 512,        Bw + (size_t)(n0 + brow) * Kd + k0 + cB * 8);
        ald16(sm.s.B + 2048 + (size_t)w * 512, Bw + (size_t)(n0 + 64 + brow) * Kd + k0 + cB * 8);
        __syncthreads();

        s16x8 af[4], bfv[4];
#pragma unroll
        for (int mi = 0; mi < 4; ++mi)
            af[mi] = *(const s16x8*)(sm.s.A + (wm + mi * 16 + fr) * 32 + sB * 8);
#pragma unroll
        for (int ni = 0; ni < 4; ++ni)
            bfv[ni] = *(const s16x8*)(sm.s.B + (wn + ni * 16 + fr) * 32 + sB * 8);
#pragma unroll
        for (int mi = 0; mi < 4; ++mi)
#pragma unroll
            for (int ni = 0; ni < 4; ++ni)
                acc[mi][ni] = MFMA_BF16(af[mi], bfv[ni], acc[mi][ni], 0, 0, 0);
        __syncthreads();
    }

    if (z != 2) {
        unsigned short* C = z ? Xk : Xq;
        const float osc = z == 0 ? QSCL : 1.0f;
#pragma unroll
        for (int mi = 0; mi < 4; ++mi)
#pragma unroll
            for (int ni = 0; ni < 4; ++ni)
#pragma unroll
                for (int reg = 0; reg < 4; ++reg)
                    C[(size_t)(m0 + wm + mi * 16 + g * 4 + reg) * 1024 +
                      n0 + wn + ni * 16 + fr] = f2bf(acc[mi][ni][reg] * osc);
    } else {
        unsigned short* T = sm.T + w * (64 * 68);
#pragma unroll
        for (int mi = 0; mi < 4; ++mi)
#pragma unroll
            for (int ni = 0; ni < 4; ++ni) {
                uint2 u;
                u.x = pk2h(acc[mi][ni][0], acc[mi][ni][1]);
                u.y = pk2h(acc[mi][ni][2], acc[mi][ni][3]);
                *(uint2*)(T + (ni * 16 + fr) * 68 + mi * 16 + g * 4) = u;
            }
        __asm__ __volatile__("" ::: "memory");
#pragma unroll
        for (int pass = 0; pass < 8; ++pass) {
            const int row = pass * 8 + (lane >> 3);
            const int chk = lane & 7;
            uint4 d = *(const uint4*)(T + row * 68 + chk * 8);
            *(uint4*)(Xvt + (size_t)(n0 + wn + row) * 4096 + m0 + wm + chk * 8) = d;
        }
    }
}

// ---------------------------------------------------------------------------
// flash attention, KEY-SPLIT. grid (32 bh, 32 qt desc), 3 blocks/CU.
// Wave w: keys [w*16,(w+1)*16) of each 64-key tile, partial O/l for all 64 q.
// S^T: 2 MFMA 16x16x32 per q-group (kf = 2 b128/wave). PV: zero-padded
// 16x16x32, P converted in-register (no LDS roundtrip). vf = 4 b64/wave.
// Epilogue: 2-round cross-wave tree reduction through a 34KB LDS union.
// ---------------------------------------------------------------------------
__global__ __launch_bounds__(256, 3) void flash_attn_kernel(
        const unsigned short* __restrict__ Xq, const unsigned short* __restrict__ Xk,
        const unsigned short* __restrict__ Xvt, unsigned short* __restrict__ Oa) {
    __shared__ union {
        struct { unsigned short K[64 * 64]; unsigned short V[64 * 64]; } s;
        struct { float o[2][16][64][4]; float l[2][64][4]; } r;   // 34KB epilogue
    } sm;

    const int t = threadIdx.x;
    const int bh = blockIdx.x;                 // fast dim -> XCD-local K/V
    const int qt = 31 - (int)blockIdx.y;       // descending: LPT (queue exists at 3/CU)
    const int b = bh >> 4, h = bh & 15;
    const size_t rbase = (size_t)b * 2048;
    const int cbase = h * 64;

    const int w = t >> 6, lane = t & 63, fr = lane & 15, g = lane >> 4;

    // Q fragments for all 4 q-groups (B-operand of S^T)
    s16x8 qf[4][2];
#pragma unroll
    for (int qg = 0; qg < 4; ++qg) {
        const unsigned short* qp = Xq + (rbase + qt * 64 + qg * 16 + fr) * 1024 + cbase;
        qf[qg][0] = *(const s16x8*)(qp + g * 8);
        qf[qg][1] = *(const s16x8*)(qp + 32 + g * 8);
    }

    float lacc[4] = {0.f, 0.f, 0.f, 0.f};
    f32x4 oacc[4][4] = {};    // [mt d-tile][qg]

    // staging (identical image to r10: slot s of row r holds source chunk s^(r&7))
    const int r0 = w * 16 + (lane >> 3), r1 = r0 + 8;
    const int s8l = lane & 7;
    const int c0 = s8l ^ (r0 & 7), c1 = s8l ^ (r1 & 7);
    const unsigned short* kbase = Xk + rbase * 1024 + cbase;
    const size_t vrow0 = (size_t)(cbase + r0) * 4096 + rbase + c0 * 8;
    const size_t vrow1 = (size_t)(cbase + r1) * 4096 + rbase + c1 * 8;

    uint4 kA = *(const uint4*)(kbase + (size_t)r0 * 1024 + c0 * 8);
    uint4 kB = *(const uint4*)(kbase + (size_t)r1 * 1024 + c1 * 8);
    uint4 vA = *(const uint4*)(Xvt + vrow0);
    uint4 vB = *(const uint4*)(Xvt + vrow1);

    unsigned short* Kls = sm.s.K;
    unsigned short* Vls = sm.s.V;
    const int rowK = w * 16 + fr;                        // this wave's key row
    const int kslot0 = (g ^ (fr & 7)) * 8;               // d 0..31 chunk
    const int kslot1 = ((4 + g) ^ (fr & 7)) * 8;         // d 32..63 chunk
    const int vchunk = 2 * w + (g >> 1);                 // key chunk within row

    for (int kt = 0; kt <= qt; ++kt) {
        *(uint4*)(Kls + (w * 16) * 64 + lane * 8)     = kA;
        *(uint4*)(Kls + (w * 16 + 8) * 64 + lane * 8) = kB;
        *(uint4*)(Vls + (w * 16) * 64 + lane * 8)     = vA;
        *(uint4*)(Vls + (w * 16 + 8) * 64 + lane * 8) = vB;
        __syncthreads();

        if (kt < qt) {   // register prefetch of kt+1 (hidden by compute)
            const unsigned short* ks = kbase + (size_t)(kt + 1) * 65536;
            kA = *(const uint4*)(ks + (size_t)r0 * 1024 + c0 * 8);
            kB = *(const uint4*)(ks + (size_t)r1 * 1024 + c1 * 8);
            vA = *(const uint4*)(Xvt + vrow0 + (size_t)(kt + 1) * 64);
            vB = *(const uint4*)(Xvt + vrow1 + (size_t)(kt + 1) * 64);
        }

        // K fragments: this wave's 16 keys x 64 d (2 b128)
        s16x8 kf0 = *(const s16x8*)(Kls + rowK * 64 + kslot0);
        s16x8 kf1 = *(const s16x8*)(Kls + rowK * 64 + kslot1);
        // V fragments: 4 d-tiles x wave's keys, zero-padded upper half (4 b64)
        uint4 vfp[4];
#pragma unroll
        for (int mt = 0; mt < 4; ++mt) {
            uint2 d2 = *(const uint2*)(Vls + (mt * 16 + fr) * 64 +
                                       ((vchunk ^ (fr & 7)) * 8) + (g & 1) * 4);
            vfp[mt].x = d2.x; vfp[mt].y = d2.y; vfp[mt].z = 0u; vfp[mt].w = 0u;
        }

        const bool diag = (kt == qt);
#pragma unroll
        for (int qg = 0; qg < 4; ++qg) {
            if (diag && w > qg) continue;      // all keys > all q: fully masked
            f32x4 zz = {};
            zz = MFMA_BF16(kf0, qf[qg][0], zz, 0, 0, 0);
            f32x4 sf = MFMA_BF16(kf1, qf[qg][1], zz, 0, 0, 0);
            float e[4];
            const bool edge = diag && (w == qg);
#pragma unroll
            for (int r = 0; r < 4; ++r)
                e[r] = (!edge || (g * 4 + r <= fr)) ? exp2f(sf[r]) : 0.f;
            lacc[qg] += e[0] + e[1] + e[2] + e[3];
            uint4 pu;
            pu.x = pk2h(e[0], e[1]); pu.y = pk2h(e[2], e[3]); pu.z = 0u; pu.w = 0u;
            const s16x8 pf = *(const s16x8*)&pu;
#pragma unroll
            for (int mt = 0; mt < 4; ++mt)
                oacc[mt][qg] = MFMA_BF16(*(const s16x8*)&vfp[mt], pf,
                                         oacc[mt][qg], 0, 0, 0);
        }
        __syncthreads();
    }

    // ---- cross-wave reduction (waves hold disjoint key subsets) ----
    auto wrbuf = [&](int bi) {
#pragma unroll
        for (int mt = 0; mt < 4; ++mt)
#pragma unroll
            for (int qg = 0; qg < 4; ++qg)
                *(f32x4*)&sm.r.o[bi][mt * 4 + qg][lane][0] = oacc[mt][qg];
        f32x4 lv = {lacc[0], lacc[1], lacc[2], lacc[3]};
        *(f32x4*)&sm.r.l[bi][lane][0] = lv;
    };
    auto rdbuf = [&](int bi) {
#pragma unroll
        for (int mt = 0; mt < 4; ++mt)
#pragma unroll
            for (int qg = 0; qg < 4; ++qg)
                oacc[mt][qg] += *(const f32x4*)&sm.r.o[bi][mt * 4 + qg][lane][0];
        f32x4 lv = *(const f32x4*)&sm.r.l[bi][lane][0];
        lacc[0] += lv[0]; lacc[1] += lv[1]; lacc[2] += lv[2]; lacc[3] += lv[3];
    };
    if (w == 1) wrbuf(0);
    if (w == 3) wrbuf(1);
    __syncthreads();
    if (w == 0) rdbuf(0);
    if (w == 2) rdbuf(1);
    __syncthreads();
    if (w == 2) wrbuf(0);
    __syncthreads();
    if (w == 0) {
        rdbuf(0);
#pragma unroll
        for (int qg = 0; qg < 4; ++qg) {
            lacc[qg] += __shfl_xor(lacc[qg], 16, 64);
            lacc[qg] += __shfl_xor(lacc[qg], 32, 64);
        }
#pragma unroll
        for (int qg = 0; qg < 4; ++qg) {
            const float inv = 1.0f / lacc[qg];
            const size_t row = rbase + qt * 64 + qg * 16 + fr;
#pragma unroll
            for (int mt = 0; mt < 4; ++mt) {
                uint2 u;
                u.x = pk2h(oacc[mt][qg][0] * inv, oacc[mt][qg][1] * inv);
                u.y = pk2h(oacc[mt][qg][2] * inv, oacc[mt][qg][3] * inv);
                *(uint2*)(Oa + row * 1024 + cbase + mt * 16 + g * 4) = u;
            }
        }
    }
}

// ---------------------------------------------------------------------------
// outproj: out_fp32[4096x1024] = Oa_bf16 @ Wo_bf16^T. 64x128 tile, BK=32,
// full ald16 staging. grid (64, 8): x->m (XCD-local A), y->n.
// ---------------------------------------------------------------------------
__global__ __launch_bounds__(256) void outproj_kernel(
        const unsigned short* __restrict__ Oa, const unsigned short* __restrict__ Wo,
        float* __restrict__ out) {
    constexpr int Kd = 1024;
    __shared__ unsigned short lsA[64 * 32];
    __shared__ unsigned short lsB[128 * 32];

    const int t = threadIdx.x;
    const int m0 = blockIdx.x * 64, n0 = blockIdx.y * 128;
    const int w = t >> 6, lane = t & 63, fr = lane & 15, g = lane >> 4;
    const int wm = (w >> 1) * 32, wn = (w & 1) * 64;
    const int brow = t >> 2;
    const int cB = (t & 3) ^ ((t >> 3) & 3);
    const int sB = g ^ ((fr >> 1) & 3);

    f32x4 acc[2][4] = {};

    for (int k0 = 0; k0 < Kd; k0 += 32) {
        ald16(lsA + (size_t)w * 512,        Oa + (size_t)(m0 + brow) * Kd + k0 + cB * 8);
        ald16(lsB + (size_t)w * 512,        Wo + (size_t)(n0 + brow) * Kd + k0 + cB * 8);
        ald16(lsB + 2048 + (size_t)w * 512, Wo + (size_t)(n0 + 64 + brow) * Kd + k0 + cB * 8);
        __syncthreads();

        s16x8 af[2], bfv[4];
#pragma unroll
        for (int mi = 0; mi < 2; ++mi)
            af[mi] = *(const s16x8*)(lsA + (wm + mi * 16 + fr) * 32 + sB * 8);
#pragma unroll
        for (int ni = 0; ni < 4; ++ni)
            bfv[ni] = *(const s16x8*)(lsB + (wn + ni * 16 + fr) * 32 + sB * 8);
#pragma unroll
        for (int mi = 0; mi < 2; ++mi)
#pragma unroll
            for (int ni = 0; ni < 4; ++ni)
                acc[mi][ni] = MFMA_BF16(af[mi], bfv[ni], acc[mi][ni], 0, 0, 0);
        __syncthreads();
    }

#pragma unroll
    for (int mi = 0; mi < 2; ++mi)
#pragma unroll
        for (int ni = 0; ni < 4; ++ni)
#pragma unroll
            for (int reg = 0; reg < 4; ++reg)
                out[(size_t)(m0 + wm + mi * 16 + g * 4 + reg) * 1024 +
                    n0 + wn + ni * 16 + fr] = acc[mi][ni][reg];
}

// ---------------------------------------------------------------------------
extern "C" void kernel_launch(void* const* d_in, const int* in_sizes, int n_in,
                              void* d_out, int out_size, void* d_ws, size_t ws_size,
                              hipStream_t stream) {
    const float* q  = (const float*)d_in[0];
    const float* k  = (const float*)d_in[1];
    const float* v  = (const float*)d_in[2];
    const float* wq = (const float*)d_in[3];
    const float* wk = (const float*)d_in[4];
    const float* wv = (const float*)d_in[5];
    const float* wo = (const float*)d_in[6];
    float* out = (float*)d_out;

    // ws layout (shorts): Qb 0 | Kb 4M | Vb 8M | Wb 12M (4x1M) | Xq 16M |
    //                     Xk 20M | Xvt 24M | Oa 28M   (= 64 MB)
    unsigned short* base = (unsigned short*)d_ws;
    unsigned short* Qb  = base;
    unsigned short* Kb  = base + 4194304;
    unsigned short* Vb  = base + 8388608;
    unsigned short* Wb  = base + 12582912;
    unsigned short* Xq  = base + 16777216;
    unsigned short* Xk  = base + 20971520;
    unsigned short* Xvt = base + 25165824;
    unsigned short* Oa  = base + 29360128;

    convert_all_kernel<<<8192, 256, 0, stream>>>(q, k, v, wq, wk, wv, wo, base);
    proj3b_kernel<<<dim3(32, 8, 3), 256, 0, stream>>>(Qb, Kb, Vb, Wb, Xq, Xk, Xvt);
    flash_attn_kernel<<<dim3(32, 32), 256, 0, stream>>>(Xq, Xk, Xvt, Oa);
    outproj_kernel<<<dim3(64, 8), 256, 0, stream>>>(Oa, Wb + 3145728, out);
}